// Round 12
// baseline (2308.201 us; speedup 1.0000x reference)
//
#include <hip/hip_runtime.h>
#include <math.h>

#define B_      4
#define F_BINS  128
#define T_FULL  16384
#define KF      33
#define KT      129

// conv tile geometry: f-tile 32 planes x TT 128 t per block
#define TT      128
#define ROWS    260                // TT + 132 halo
#define PITCH   72                 // ushort pitch for 64 f cols (16B-aligned rows)
#define DTP     136                // padded dt rows (129 + prefetch overrun pad)
#define D2F     48                 // F d2 window (frag u at 8u, u=0..4 used)
#define D2G     40                 // G d2 window (5 x 8)

typedef __attribute__((ext_vector_type(8))) short short8;
typedef __attribute__((ext_vector_type(4))) float f32x4;
typedef uint uint4a16 __attribute__((ext_vector_type(4), aligned(16)));

union ABFrag { uint4a16 u; short8 v; };

__device__ __forceinline__ ushort f2bf(float v) {
  unsigned u = __float_as_uint(v);
  unsigned r = (u + 0x7FFFu + ((u >> 16) & 1u)) >> 16;
  return (ushort)r;
}

__device__ __forceinline__ short8 load_a16(const ushort* p) {
  ABFrag f; f.u = *(const uint4a16*)p; return f.v;
}

// ---------------------------------------------------------------------------
// prep_wF: wq[oct 4][fp 4][ch 16][dt 136][d2 48] = wav[ch][df = d2 - 4 - fp][dt]
//          (round-7 F layout)
// prep_wG: wg[oct 4][fp 4][ch 16][dt 136][d2 40] = wav[ch][df = d2 - fp][dt]
//          (memory copy of round-7's G = F shifted +4 in d2)
// zero outside df in [0,33), dt in [0,129).
// ---------------------------------------------------------------------------
__global__ __launch_bounds__(256) void prep_wF(
    const float* __restrict__ wr, const float* __restrict__ wi,
    ushort* __restrict__ wq) {
  int idx = blockIdx.x * 256 + threadIdx.x;      // 4*4*16*136*48 = 1671168
  int d2  = idx % D2F;
  int dt  = (idx / D2F) % DTP;
  int ch  = (idx / (D2F * DTP)) % 16;
  int fp  = (idx / (D2F * DTP * 16)) % 4;
  int oct = idx / (D2F * DTP * 16 * 4);
  int df  = d2 - 4 - fp;
  float v = 0.f;
  if (df >= 0 && df < KF && dt < KT) {
    const float* src = (ch < 8) ? wr : wi;
    v = src[(((size_t)oct * 8 + (ch & 7)) * KF + df) * KT + dt];
  }
  wq[idx] = f2bf(v);
}

__global__ __launch_bounds__(256) void prep_wG(
    const float* __restrict__ wr, const float* __restrict__ wi,
    ushort* __restrict__ wg) {
  int idx = blockIdx.x * 256 + threadIdx.x;      // 4*4*16*136*40 = 1392640
  int d2  = idx % D2G;
  int dt  = (idx / D2G) % DTP;
  int ch  = (idx / (D2G * DTP)) % 16;
  int fp  = (idx / (D2G * DTP * 16)) % 4;
  int oct = idx / (D2G * DTP * 16 * 4);
  int df  = d2 - fp;
  float v = 0.f;
  if (df >= 0 && df < KF && dt < KT) {
    const float* src = (ch < 8) ? wr : wi;
    v = src[(((size_t)oct * 8 + (ch & 7)) * KF + df) * KT + dt];
  }
  wg[idx] = f2bf(v);
}

// ---------------------------------------------------------------------------
// prep_x: bf16 transposed pyramid  xTj[b][T_j][128f]  for j=0..3
// ---------------------------------------------------------------------------
__global__ __launch_bounds__(256) void prep_x(
    const float* __restrict__ x,
    ushort* __restrict__ xT0, ushort* __restrict__ xT1,
    ushort* __restrict__ xT2, ushort* __restrict__ xT3) {
  __shared__ float lt[128 * 65];
  const int b  = blockIdx.y;
  const int t0 = blockIdx.x * 64;
  const int tid = threadIdx.x;
  const int wv = tid >> 6, lane = tid & 63;
#pragma unroll
  for (int rep = 0; rep < 32; ++rep) {
    int f = rep * 4 + wv;
    lt[f * 65 + lane] = x[((size_t)b * 128 + f) * T_FULL + t0 + lane];
  }
  __syncthreads();
  ushort* dst[4] = {xT0, xT1, xT2, xT3};
  const int Ts[4] = {16384, 8192, 4096, 2048};
  for (int lvl = 0; lvl < 4; ++lvl) {
    int nt = 64 >> lvl, w = 1 << lvl;
    float inv = 1.f / (float)w;
    int tasks = nt * 16;
    for (int i = tid; i < tasks; i += 256) {
      int tl = i >> 4, fc = i & 15;
      __align__(16) ushort vs[8];
#pragma unroll
      for (int e = 0; e < 8; ++e) {
        float a = 0.f;
        for (int m = 0; m < w; ++m) a += lt[(fc * 8 + e) * 65 + tl * w + m];
        vs[e] = f2bf(a * inv);
      }
      ushort* pdst = dst[lvl] + ((size_t)b * Ts[lvl] + (t0 >> lvl) + tl) * 128 + fc * 8;
      *(uint4*)pdst = *(const uint4*)vs;
    }
  }
}

// ---------------------------------------------------------------------------
// conv_mfma: ALL octaves fused in one grid of 3840 equal-work blocks.
//   blocks [0,2048) oct0, [2048,3072) oct1, [3072,3584) oct2, [3584,3840) oct3
// Block = 256 thr = 4 waves; tile = 32 f_out x 128 t.
// MFMA 16x16x32_bf16: M=ch16 (A=weights), N=pos16 (B=x), K=(4 dt x 8 d2).
// Per gamma-iter computes 8 output-f planes fo = f0 + gamma + 4k (k=0..7):
//   odd  k: A = F[s - (k-1)/2] ; even k: A = G[s - k/2]
// with per-plane active s in [s_lo(k), s_lo(k)+4], s_lo = {0,0,1,1,2,2,3,3}.
// F AND G stream from memory (wq / wg) with in-place next-c prefetch at
// s = u+3 — the step of fragment u's LAST use (k=7 reads F[s-3], k=6 reads
// G[s-3], both BEFORE the overwrite in source order; proven F pattern, R7).
// Epilogue deduped: lo lanes finish r=0,1; hi lanes finish r=2,3.
// ---------------------------------------------------------------------------
__global__ __launch_bounds__(256, 3) void conv_mfma(
    const ushort* __restrict__ xT0, const ushort* __restrict__ xT1,
    const ushort* __restrict__ xT2, const ushort* __restrict__ xT3,
    const ushort* __restrict__ wq, const ushort* __restrict__ wg,
    float* __restrict__ out) {
  __shared__ ushort xt[ROWS * PITCH];
  const int tid = threadIdx.x;
  const int bx = blockIdx.x;

  int oct, local;
  if (bx < 2048)      { oct = 0; local = bx; }
  else if (bx < 3072) { oct = 1; local = bx - 2048; }
  else if (bx < 3584) { oct = 2; local = bx - 3072; }
  else                { oct = 3; local = bx - 3584; }
  const ushort* xT = (oct == 0) ? xT0 : (oct == 1) ? xT1 : (oct == 2) ? xT2 : xT3;
  const int Tj  = T_FULL >> oct;
  const int lw  = 4 - oct;                    // pool window = 1<<lw
  const int nxs = 7 - oct;
  const int tx   = local & ((1 << nxs) - 1);
  const int rest = local >> nxs;
  const int t0 = tx * TT;
  const int f0 = (rest & 3) * 32;
  const int b  = rest >> 2;

  // ---- stage transposed x tile: rows 0..259 (t = t0-64+row), cols f0-16+[0,64) ----
  for (int i = tid; i < ROWS * 8; i += 256) {
    int row = i >> 3, fc = i & 7;
    int t = t0 - 64 + row;
    int f = f0 - 16 + fc * 8;
    uint4 v = make_uint4(0u, 0u, 0u, 0u);
    if (t >= 0 && t < Tj && f >= 0 && f < 128)
      v = *(const uint4*)(xT + ((size_t)b * Tj + t) * 128 + f);
    *(uint4*)&xt[row * PITCH + fc * 8] = v;
  }
  __syncthreads();

  const int wave = tid >> 6, lane = tid & 63;
  const int p = lane & 15;                 // A-row = channel sel, B-col = position
  const int g = lane >> 4;                 // k-group (dt sub-index)
  const int hi = (lane >= 32);
  const float invw = 1.0f / (float)(1 << lw);

  for (int gamma = 0; gamma < 4; ++gamma) {
    const ushort* wbase =
        wq + ((((size_t)oct * 4 + gamma) * 16 + p) * DTP + g) * D2F;
    const ushort* wgbase =
        wg + ((((size_t)oct * 4 + gamma) * 16 + p) * DTP + g) * D2G;
    const ushort* wp  = wbase  + 4 * D2F;   // in-body F loads fetch c+1
    const ushort* wgp = wgbase + 4 * D2G;   // in-body G loads fetch c+1
    int rb = (p + g) * PITCH + wave * (32 * PITCH);

    f32x4 acc[8][2];
#pragma unroll
    for (int k = 0; k < 8; ++k)
#pragma unroll
      for (int r = 0; r < 2; ++r) { f32x4 z = {0.f, 0.f, 0.f, 0.f}; acc[k][r] = z; }

    short8 F[5], G[5];
#pragma unroll
    for (int u = 0; u < 5; ++u) F[u] = load_a16(wbase + 8 * u);
#pragma unroll
    for (int u = 0; u < 5; ++u) G[u] = load_a16(wgbase + 8 * u);

#pragma unroll 1
    for (int c = 0; c < 33; ++c) {
      __builtin_amdgcn_s_setprio(1);
      const int SLO[8] = {0, 0, 1, 1, 2, 2, 3, 3};
#pragma unroll
      for (int s = 0; s < 8; ++s) {
        short8 bv0 = *(const short8*)&xt[rb + s * 8];
        short8 bv1 = *(const short8*)&xt[rb + 16 * PITCH + s * 8];
#pragma unroll
        for (int k = 0; k < 8; ++k) {
          if (s >= SLO[k] && s <= SLO[k] + 4) {
            const int idx = s - SLO[k];
            short8 a = (k & 1) ? F[idx] : G[idx];
            acc[k][0] = __builtin_amdgcn_mfma_f32_16x16x32_bf16(a, bv0, acc[k][0], 0, 0, 0);
            acc[k][1] = __builtin_amdgcn_mfma_f32_16x16x32_bf16(a, bv1, acc[k][1], 0, 0, 0);
          }
        }
        // in-place prefetch of next-c fragments, at the step of last use
        // (k=7 / k=6 read F[s-3] / G[s-3] above, before these writes)
        if (s >= 3) {
          F[s - 3] = load_a16(wp  + 8 * (s - 3));
          G[s - 3] = load_a16(wgp + 8 * (s - 3));
        }
      }
      __builtin_amdgcn_s_setprio(0);
      wp  += 4 * D2F;              // dt += 4
      wgp += 4 * D2G;
      rb  += 4 * PITCH;
    }

    // ---- epilogue: modulus + avg-pool, deduped across lane halves ----
#pragma unroll
    for (int k = 0; k < 8; ++k) {
      const int fo = f0 + gamma + 4 * k;
#pragma unroll
      for (int fr = 0; fr < 2; ++fr) {
        const int tbase = t0 + 32 * wave + 16 * fr;
        float sq[4];
#pragma unroll
        for (int r = 0; r < 4; ++r) {
          float a = acc[k][fr][r];
          float o = __shfl_xor(a, 32);
          sq[r] = a * a + o * o;
        }
        float m0 = sqrtf(hi ? sq[2] : sq[0]);
        float m1 = sqrtf(hi ? sq[3] : sq[1]);
        if (lw == 4) { m0 += __shfl_xor(m0, 8); m1 += __shfl_xor(m1, 8); }
        if (lw >= 3) { m0 += __shfl_xor(m0, 4); m1 += __shfl_xor(m1, 4); }
        if (lw >= 2) { m0 += __shfl_xor(m0, 2); m1 += __shfl_xor(m1, 2); }
        m0 += __shfl_xor(m0, 1);  m1 += __shfl_xor(m1, 1);
        if ((p & ((1 << lw) - 1)) == 0) {
          const int ch0 = 4 * (g & 1) + (hi ? 2 : 0);
          const int tcol = (tbase + p) >> lw;
          size_t o0 = (((size_t)b * 32 + oct * 8 + ch0) * 128 + fo) * 1024 + tcol;
          out[o0] = m0 * invw;
          out[o0 + (size_t)128 * 1024] = m1 * invw;   // ch0+1
        }
      }
    }
  }
}

// ---------------------------------------------------------------------------
extern "C" void kernel_launch(void* const* d_in, const int* in_sizes, int n_in,
                              void* d_out, int out_size, void* d_ws, size_t ws_size,
                              hipStream_t stream) {
  const float* x  = (const float*)d_in[0];
  const float* wr = (const float*)d_in[1];
  const float* wi = (const float*)d_in[2];
  float* out = (float*)d_out;

  ushort* xT0 = (ushort*)d_ws;                       // 4*16384*128
  ushort* xT1 = xT0 + (size_t)4 * 16384 * 128;       // 4*8192*128
  ushort* xT2 = xT1 + (size_t)4 * 8192 * 128;        // 4*4096*128
  ushort* xT3 = xT2 + (size_t)4 * 4096 * 128;        // 4*2048*128
  ushort* wq  = xT3 + (size_t)4 * 2048 * 128;        // 1671168
  ushort* wgm = wq + (size_t)1671168;                // 1392640

  prep_wF<<<1671168 / 256, 256, 0, stream>>>(wr, wi, wq);
  prep_wG<<<1392640 / 256, 256, 0, stream>>>(wr, wi, wgm);
  prep_x<<<dim3(T_FULL / 64, B_), 256, 0, stream>>>(x, xT0, xT1, xT2, xT3);

  conv_mfma<<<3840, 256, 0, stream>>>(xT0, xT1, xT2, xT3, wq, wgm, out);
}